// Round 12
// baseline (1038.695 us; speedup 1.0000x reference)
//
#include <hip/hip_runtime.h>
#include <cstdint>
#include <cstddef>

typedef _Float16 f16;
typedef __attribute__((ext_vector_type(2))) _Float16 f16x2;
typedef __attribute__((ext_vector_type(4))) _Float16 f16x4;
typedef __attribute__((ext_vector_type(8))) _Float16 f16x8;
typedef __attribute__((ext_vector_type(4))) float f32x4;

#define MFMA_16x16x32(a,b,c) __builtin_amdgcn_mfma_f32_16x16x32_f16((a),(b),(c),0,0,0)
#define MFMA_16x16x16(a,b,c) __builtin_amdgcn_mfma_f32_16x16x16f16((a),(b),(c),0,0,0)

#define NSEQ 384
#define CIN 128
#define NH 4
#define DHD 32
#define RNK 96
#define SDIM 449
#define MHID 256
#define NN (NSEQ*NSEQ)
#define LOG2E 1.4426950408889634f

#define KPAD 608            // 577 padded to 19*32
#define ZSTR 616            // LDS stride for z (2-way bank aliasing only)
#define HSTR 264            // LDS stride for h1/h2
// f16 transposed-weight pool offsets (elements)
#define OFF_W1 0
#define SZ_W1 (MHID*KPAD)          // 155648 per matrix
#define OFF_W2 (2*SZ_W1)           // 311296
#define SZ_W2 (MHID*MHID)          // 65536
#define OFF_W3 (OFF_W2 + 2*SZ_W2)  // 442368
#define SZ_W3 ((NH*RNK)*MHID)      // 98304
#define WMLP_TOT (OFF_W3 + 2*SZ_W3) // 638976

// ---------------- weight conversion: W4T[col][k] = W*[k][col&127] (f16), WoT[c][hd] = Wo[hd][c]
__global__ __launch_bounds__(256) void k_convert(const float* __restrict__ Wq, const float* __restrict__ Wk,
    const float* __restrict__ Wv, const float* __restrict__ Wg, const float* __restrict__ Wo,
    f16* __restrict__ W4T, f16* __restrict__ WoT) {
  int idx = blockIdx.x*256 + threadIdx.x;   // 0..81919 (640*128)
  int c = idx >> 7, kk = idx & 127;
  if (c < 512) {
    int mat = c >> 7, cc = c & 127;
    const float* src = mat==0 ? Wq : (mat==1 ? Wk : (mat==2 ? Wv : Wg));
    W4T[c*CIN + kk] = (f16)src[kk*CIN + cc];
  } else {
    int cc = c - 512;
    WoT[cc*CIN + kk] = (f16)Wo[kk*CIN + cc];
  }
}

// ---------------- MLP weight transpose+cast into one f16 pool (coalesced writes)
__global__ __launch_bounds__(256) void k_convert2(const float* __restrict__ Wq1, const float* __restrict__ Wq2,
    const float* __restrict__ Wq3, const float* __restrict__ Wk1, const float* __restrict__ Wk2,
    const float* __restrict__ Wk3, f16* __restrict__ wmlp) {
  int idx = blockIdx.x*256 + threadIdx.x;   // 0..638975
  float val;
  if (idx < OFF_W2) {
    int m = idx / SZ_W1, r = idx - m*SZ_W1;
    int c = r / KPAD, kk = r - c*KPAD;
    const float* src = m ? Wk1 : Wq1;
    val = (kk < SDIM + CIN) ? src[kk*MHID + c] : 0.f;
  } else if (idx < OFF_W3) {
    int r = idx - OFF_W2;
    int m = r >> 16, rr = r & 65535;
    int c = rr >> 8, kk = rr & 255;
    const float* src = m ? Wk2 : Wq2;
    val = src[kk*MHID + c];
  } else {
    int r = idx - OFF_W3;
    int m = r / SZ_W3, rr = r - m*SZ_W3;
    int c = rr >> 8, kk = rr & 255;
    const float* src = m ? Wk3 : Wq3;
    val = src[kk*(NH*RNK) + c];
  }
  wmlp[idx] = (f16)val;
}

// ---------------- layernorm + row-mean contribution. 4 blocks per row i; wave handles 2 rows/iter
__global__ __launch_bounds__(256) void k_ln(const float* __restrict__ x, const float* __restrict__ gamma,
    const float* __restrict__ beta, f16* __restrict__ xn, float* __restrict__ rowm) {
  int b = blockIdx.x;
  int i = b >> 2, jbase = (b & 3) * 96;
  int t = threadIdx.x, wave = t >> 6, lane = t & 63;
  int half = lane >> 5, l31 = lane & 31;
  int c0 = l31 * 4;
  __shared__ float racc[CIN];
  if (t < CIN) racc[t] = 0.f;
  float4 g4 = *(const float4*)&gamma[c0];
  float4 b4 = *(const float4*)&beta[c0];
  float a0=0,a1=0,a2=0,a3=0;
  __syncthreads();
  for (int it = 0; it < 12; ++it) {
    int j = jbase + it*8 + wave*2 + half;
    const float4 v = *(const float4*)&x[(size_t)(i*NSEQ + j)*CIN + c0];
    float s = (v.x+v.y)+(v.z+v.w);
    float ss = (v.x*v.x+v.y*v.y)+(v.z*v.z+v.w*v.w);
#pragma unroll
    for (int off = 16; off >= 1; off >>= 1) { s += __shfl_xor(s, off); ss += __shfl_xor(ss, off); }
    float mean = s * (1.0f/CIN);
    float var = ss * (1.0f/CIN) - mean*mean;
    float rs = rsqrtf(var + 1e-5f);
    float y0 = (v.x-mean)*rs*g4.x + b4.x;
    float y1 = (v.y-mean)*rs*g4.y + b4.y;
    float y2 = (v.z-mean)*rs*g4.z + b4.z;
    float y3 = (v.w-mean)*rs*g4.w + b4.w;
    f16x4 w; w[0]=(f16)y0; w[1]=(f16)y1; w[2]=(f16)y2; w[3]=(f16)y3;
    *(f16x4*)&xn[(size_t)(i*NSEQ + j)*CIN + c0] = w;
    a0+=y0; a1+=y1; a2+=y2; a3+=y3;
  }
  atomicAdd(&racc[c0], a0); atomicAdd(&racc[c0+1], a1);
  atomicAdd(&racc[c0+2], a2); atomicAdd(&racc[c0+3], a3);
  __syncthreads();
  if (t < CIN) atomicAdd(&rowm[i*CIN + t], racc[t] * (1.0f/NSEQ));
}

// ---------------- column means v2 (mean over axis 0), f16x8 vector loads. 16 slices x 24 rows.
__global__ __launch_bounds__(256) void k_colmean(const f16* __restrict__ xn, float* __restrict__ colm) {
  int j = blockIdx.x; int t = threadIdx.x;
  int cg = (t & 15) * 8;      // channel group base (16 groups x 8 ch)
  int s  = t >> 4;            // slice 0..15, 24 rows each
  float acc[8];
#pragma unroll
  for (int u = 0; u < 8; ++u) acc[u] = 0.f;
  int i0 = s * 24;
  for (int ii = i0; ii < i0 + 24; ++ii) {
    f16x8 v = *(const f16x8*)&xn[(size_t)(ii*NSEQ + j)*CIN + cg];
#pragma unroll
    for (int u = 0; u < 8; ++u) acc[u] += (float)v[u];
  }
  __shared__ float sb[16][CIN];
#pragma unroll
  for (int u = 0; u < 8; ++u) sb[s][cg + u] = acc[u];
  __syncthreads();
  if (t < 128) {
    float r = 0.f;
#pragma unroll
    for (int s2 = 0; s2 < 16; ++s2) r += sb[s2][t];
    colm[j*CIN + t] = r * (1.0f/NSEQ);
  }
}

// ---------------- fused bias MLP (MFMA): 32 rows/block, 3 layers block-local. fp32 qbT/kbT out.
__global__ __launch_bounds__(256) void k_mlp2(const float* __restrict__ rowm, const float* __restrict__ colm,
    const float* __restrict__ sinp, const f16* __restrict__ wmlp,
    float* __restrict__ qbT, float* __restrict__ kbT) {
  int b = blockIdx.x;
  bool isQ = b < 12;
  int r0 = (isQ ? b : b - 12) * 32;
  const float* mean = isQ ? rowm : colm;
  const f16* W1T = wmlp + (isQ ? 0 : SZ_W1);
  const f16* W2T = wmlp + OFF_W2 + (isQ ? 0 : SZ_W2);
  const f16* W3T = wmlp + OFF_W3 + (isQ ? 0 : SZ_W3);
  float* outp = isQ ? qbT : kbT;
  int t = threadIdx.x, wave = t >> 6, lane = t & 63;
  int l15 = lane & 15, quad = lane >> 4;
  int rt = wave & 1, ch = wave >> 1;   // row-tile, col-half

  __shared__ __align__(16) f16 z[32*ZSTR];
  __shared__ __align__(16) f16 hbuf[2][32*HSTR];

  for (int idx = t; idx < 32*KPAD; idx += 256) {
    int row = idx / KPAD, u = idx - row*KPAD;
    float v;
    if (u < CIN) v = mean[(r0+row)*CIN + u];
    else if (u < CIN + SDIM) v = sinp[(r0+row)*SDIM + (u - CIN)];
    else v = 0.f;
    z[row*ZSTR + u] = (f16)v;
  }
  __syncthreads();

  {
    f32x4 acc[8];
#pragma unroll
    for (int c = 0; c < 8; ++c) acc[c] = (f32x4){0,0,0,0};
    for (int ks = 0; ks < 19; ++ks) {
      f16x8 af = *(const f16x8*)&z[(rt*16 + l15)*ZSTR + ks*32 + quad*8];
#pragma unroll
      for (int c = 0; c < 8; ++c) {
        f16x8 bf = *(const f16x8*)&W1T[(size_t)((ch*8 + c)*16 + l15)*KPAD + ks*32 + quad*8];
        acc[c] = MFMA_16x16x32(af, bf, acc[c]);
      }
    }
#pragma unroll
    for (int c = 0; c < 8; ++c) {
      int col = (ch*8 + c)*16 + l15;
#pragma unroll
      for (int r = 0; r < 4; ++r) {
        float th = 1.f - 2.f/(1.f + __expf(2.f*acc[c][r]));
        hbuf[0][(rt*16 + quad*4 + r)*HSTR + col] = (f16)th;
      }
    }
  }
  __syncthreads();

  {
    f32x4 acc[8];
#pragma unroll
    for (int c = 0; c < 8; ++c) acc[c] = (f32x4){0,0,0,0};
    for (int ks = 0; ks < 8; ++ks) {
      f16x8 af = *(const f16x8*)&hbuf[0][(rt*16 + l15)*HSTR + ks*32 + quad*8];
#pragma unroll
      for (int c = 0; c < 8; ++c) {
        f16x8 bf = *(const f16x8*)&W2T[(size_t)((ch*8 + c)*16 + l15)*MHID + ks*32 + quad*8];
        acc[c] = MFMA_16x16x32(af, bf, acc[c]);
      }
    }
#pragma unroll
    for (int c = 0; c < 8; ++c) {
      int col = (ch*8 + c)*16 + l15;
#pragma unroll
      for (int r = 0; r < 4; ++r) {
        float th = 1.f - 2.f/(1.f + __expf(2.f*acc[c][r]));
        hbuf[1][(rt*16 + quad*4 + r)*HSTR + col] = (f16)th;
      }
    }
  }
  __syncthreads();

  {
    f32x4 acc[12];
#pragma unroll
    for (int c = 0; c < 12; ++c) acc[c] = (f32x4){0,0,0,0};
    for (int ks = 0; ks < 8; ++ks) {
      f16x8 af = *(const f16x8*)&hbuf[1][(rt*16 + l15)*HSTR + ks*32 + quad*8];
#pragma unroll
      for (int c = 0; c < 12; ++c) {
        f16x8 bf = *(const f16x8*)&W3T[(size_t)((ch*12 + c)*16 + l15)*MHID + ks*32 + quad*8];
        acc[c] = MFMA_16x16x32(af, bf, acc[c]);
      }
    }
#pragma unroll
    for (int c = 0; c < 12; ++c) {
      int o = (ch*12 + c)*16 + l15;
#pragma unroll
      for (int r = 0; r < 4; ++r)
        outp[o*NSEQ + r0 + rt*16 + quad*4 + r] = acc[c][r];
    }
  }
}

// ---------------- low-rank bias outer product into MFMA C-fragment layout (fp32, pre-scaled by LOG2E):
// bias4[h][k>>2][q][k&3]; block = (h, kgroup), 128 threads x 3 q each.
__global__ __launch_bounds__(128) void k_bias(const float* __restrict__ qbT, const float* __restrict__ kbT,
    float* __restrict__ bias4) {
  int b = blockIdx.x;            // h*96 + kg
  int h = b / 96, kg = b - h*96;
  int t = threadIdx.x;
  __shared__ float4 kr[RNK];
  if (t < RNK) kr[t] = *(const float4*)&kbT[(size_t)(h*RNK + t)*NSEQ + kg*4];
  __syncthreads();
  float acc[3][4];
#pragma unroll
  for (int m = 0; m < 3; ++m)
#pragma unroll
    for (int r = 0; r < 4; ++r) acc[m][r] = 0.f;
  for (int r = 0; r < RNK; ++r) {
    float4 kv = kr[r];
    const float* qrow = qbT + (size_t)(h*RNK + r)*NSEQ;
    float q0 = qrow[t], q1 = qrow[t+128], q2 = qrow[t+256];
    acc[0][0]+=q0*kv.x; acc[0][1]+=q0*kv.y; acc[0][2]+=q0*kv.z; acc[0][3]+=q0*kv.w;
    acc[1][0]+=q1*kv.x; acc[1][1]+=q1*kv.y; acc[1][2]+=q1*kv.z; acc[1][3]+=q1*kv.w;
    acc[2][0]+=q2*kv.x; acc[2][1]+=q2*kv.y; acc[2][2]+=q2*kv.z; acc[2][3]+=q2*kv.w;
  }
#pragma unroll
  for (int m = 0; m < 3; ++m) {
    int q = t + m*128;
    f32x4 w; w[0]=acc[m][0]*LOG2E; w[1]=acc[m][1]*LOG2E; w[2]=acc[m][2]*LOG2E; w[3]=acc[m][3]*LOG2E;
    *(f32x4*)&bias4[((size_t)b*NSEQ + q)*4] = w;
  }
}

// ---------------- projections (round-3 proven version): hybrid A-in-regs + B-in-LDS.
__global__ __launch_bounds__(256) void k_proj(const f16* __restrict__ xn, const f16* __restrict__ W4T,
    const float* __restrict__ bg, f16* __restrict__ qb, f16* __restrict__ kb, f16* __restrict__ vb,
    f16* __restrict__ gb) {
  int mb = blockIdx.x;              // 0..1151
  int t = threadIdx.x, wave = t >> 6, lane = t & 63;
  int l15 = lane & 15, quad = lane >> 4;
  int m0 = wave*32;                 // wave's row base within the 128-row tile
  __shared__ __align__(16) f16 Bs[128*128];   // 32 KB, XOR-swizzled
  size_t grow = (size_t)mb*128 + m0;
  f16x8 af[2][4];
#pragma unroll
  for (int mt = 0; mt < 2; ++mt)
#pragma unroll
    for (int kt = 0; kt < 4; ++kt)
      af[mt][kt] = *(const f16x8*)&xn[(grow + mt*16 + l15)*CIN + (kt*4 + quad)*8];
  int i = mb/3, j0 = (mb - (mb/3)*3)*128 + m0;
  for (int nb = 0; nb < 4; ++nb) {
    for (int p = 0; p < 8; ++p) {
      int c = p*256 + t; int row = c >> 4, ci = c & 15;
      int sw = (ci ^ (row & 15)) * 8;
      *(f16x8*)&Bs[row*128 + sw] = *(const f16x8*)&W4T[(size_t)(nb*128 + row)*CIN + ci*8];
    }
    __syncthreads();
#pragma unroll
    for (int ct = 0; ct < 8; ++ct) {
      f32x4 acc0 = (f32x4){0,0,0,0}, acc1 = (f32x4){0,0,0,0};
#pragma unroll
      for (int kt = 0; kt < 4; ++kt) {
        f16x8 bf = *(const f16x8*)&Bs[(ct*16 + l15)*128 + ((kt*4 + quad) ^ l15)*8];
        acc0 = MFMA_16x16x32(af[0][kt], bf, acc0);
        acc1 = MFMA_16x16x32(af[1][kt], bf, acc1);
      }
      int col = nb*128 + ct*16 + l15;
      int cc = col & 127;
      int hh = cc >> 5, d = cc & 31;
      if (nb == 3) {
        float bgv = bg[cc];
#pragma unroll
        for (int mt = 0; mt < 2; ++mt) {
          f32x4 a = mt ? acc1 : acc0;
#pragma unroll
          for (int r = 0; r < 4; ++r) {
            int jj = j0 + mt*16 + quad*4 + r;
            float sg = 1.0f/(1.0f + __expf(-(a[r] + bgv)));
            gb[(size_t)(i*NSEQ + jj)*CIN + cc] = (f16)sg;
          }
        }
      } else {
        f16* dstb = nb==0 ? qb : (nb==1 ? kb : vb);
        float scale = nb==0 ? 0.25503576722f : 1.0f;   // log2e / sqrt(32)
#pragma unroll
        for (int mt = 0; mt < 2; ++mt) {
          f32x4 a = mt ? acc1 : acc0;
#pragma unroll
          for (int r = 0; r < 4; ++r) {
            int jj = j0 + mt*16 + quad*4 + r;
            dstb[((size_t)(i*NH + hh)*NSEQ + jj)*DHD + d] = (f16)(a[r]*scale);
          }
        }
      }
    }
    __syncthreads();
  }
}

// ---------------- attention v10: round-2 body, ONE WAVE PER BLOCK (grid 6144, 64 threads).
// The 4 waves of the 256-thread block were fully independent (no barriers/LDS); block granularity
// was limiting CU packing (measured occupancy 32% vs theoretical 75%). Single-wave blocks give
// the scheduler its finest quantum. launch_bounds(64,8): pin ~64 VGPR (known sufficient).
__global__ __launch_bounds__(64, 8) void k_attn(const f16* __restrict__ qg, const f16* __restrict__ kg,
    const f16* __restrict__ vg, const float* __restrict__ bias4, f16* __restrict__ og) {
  int b = blockIdx.x;                       // h*(NSEQ*4) + i*4 + w
  int h = b / (NSEQ*4); int r = b - h*(NSEQ*4);
  int i = r >> 2; int wave = r & 3;
  int lane = threadIdx.x & 63;
  int l15 = lane & 15, quad = lane >> 4;
  size_t base = (size_t)(i*NH + h) * NSEQ * DHD;
  int qt0 = wave*6;
  f16x8 qf[6];
#pragma unroll
  for (int s = 0; s < 6; ++s)
    qf[s] = *(const f16x8*)&qg[base + (size_t)((qt0+s)*16 + l15)*DHD + quad*8];
  f32x4 oa[6][2];
  float lsum[6];
#pragma unroll
  for (int s = 0; s < 6; ++s) { lsum[s] = 0.f; oa[s][0] = (f32x4){0,0,0,0}; oa[s][1] = (f32x4){0,0,0,0}; }
  const f16* kp = kg + base + (size_t)l15*DHD + quad*8;
  const f16* vp = vg + base + (size_t)(quad*4)*DHD + l15;
  const float* bp = bias4 + (((size_t)h*96 + quad)*NSEQ + qt0*16 + l15)*4;
  for (int kt = 0; kt < 24; ++kt) {
    f16x8 kf = *(const f16x8*)kp;
    f16x4 vf0, vf1;
#pragma unroll
    for (int jj = 0; jj < 4; ++jj) { vf0[jj] = vp[jj*DHD]; vf1[jj] = vp[jj*DHD + 16]; }
    f32x4 cb[6];
#pragma unroll
    for (int s = 0; s < 6; ++s) cb[s] = *(const f32x4*)(bp + s*64);
    kp += 16*DHD; vp += 16*DHD; bp += 4*NSEQ*4;
#pragma unroll
    for (int s = 0; s < 6; ++s) {
      f32x4 st = MFMA_16x16x32(kf, qf[s], cb[s]);   // S^T tile: row=k, col=q (bias via C-init)
      float p0 = __builtin_amdgcn_exp2f(st[0]);
      float p1 = __builtin_amdgcn_exp2f(st[1]);
      float p2 = __builtin_amdgcn_exp2f(st[2]);
      float p3 = __builtin_amdgcn_exp2f(st[3]);
      lsum[s] += (p0 + p1) + (p2 + p3);
      f16x4 pa; pa[0]=(f16)p0; pa[1]=(f16)p1; pa[2]=(f16)p2; pa[3]=(f16)p3;
      oa[s][0] = MFMA_16x16x16(pa, vf0, oa[s][0]);  // C-layout of S^T == A-layout for K=16 MFMA
      oa[s][1] = MFMA_16x16x16(pa, vf1, oa[s][1]);
    }
  }
#pragma unroll
  for (int s = 0; s < 6; ++s) {
    float lf = lsum[s];
    lf += __shfl_xor(lf, 16);
    lf += __shfl_xor(lf, 32);
    float inv = 1.0f / lf;   // valid for q = l15
#pragma unroll
    for (int r2 = 0; r2 < 4; ++r2) {
      float invr = __shfl(inv, quad*4 + r2);
      int qrow = (qt0+s)*16 + quad*4 + r2;
      size_t ob = (size_t)(i*NSEQ + qrow)*(NH*DHD) + h*DHD;
      og[ob + l15]      = (f16)(oa[s][0][r2] * invr);
      og[ob + 16 + l15] = (f16)(oa[s][1][r2] * invr);
    }
  }
}

// ---------------- final v2: out = (g*o) @ Wo + bo. A (=g*o) fragments built directly in registers
// from global; only the 32 KB WoT tile staged in LDS.
__global__ __launch_bounds__(256) void k_final(const f16* __restrict__ gb, const f16* __restrict__ ob,
    const f16* __restrict__ WoT, const float* __restrict__ bo, float* __restrict__ out) {
  int mb = blockIdx.x;
  int t = threadIdx.x, wave = t >> 6, lane = t & 63;
  int l15 = lane & 15, quad = lane >> 4;
  __shared__ __align__(16) f16 Bs[128*128];
  for (int p = 0; p < 8; ++p) {
    int c = p*256 + t; int row = c >> 4, ci = c & 15;
    int sw = (ci ^ (row & 15)) * 8;
    *(f16x8*)&Bs[row*128 + sw] = *(const f16x8*)&WoT[row*CIN + ci*8];
  }
  int m0 = wave*32;
  size_t grow = (size_t)mb*128 + m0;
  f16x8 af[2][4];
#pragma unroll
  for (int mt = 0; mt < 2; ++mt)
#pragma unroll
    for (int kt = 0; kt < 4; ++kt) {
      size_t off = (grow + mt*16 + l15)*CIN + (kt*4 + quad)*8;
      f16x8 gv = *(const f16x8*)&gb[off];
      f16x8 ov = *(const f16x8*)&ob[off];
      af[mt][kt] = gv*ov;
    }
  __syncthreads();
#pragma unroll
  for (int ct = 0; ct < 8; ++ct) {
    f32x4 acc0 = (f32x4){0,0,0,0}, acc1 = (f32x4){0,0,0,0};
#pragma unroll
    for (int kt = 0; kt < 4; ++kt) {
      f16x8 bf = *(const f16x8*)&Bs[(ct*16 + l15)*128 + ((kt*4 + quad) ^ l15)*8];
      acc0 = MFMA_16x16x32(af[0][kt], bf, acc0);
      acc1 = MFMA_16x16x32(af[1][kt], bf, acc1);
    }
    float bov = bo[ct*16 + l15];
#pragma unroll
    for (int mt = 0; mt < 2; ++mt) {
      f32x4 a = mt ? acc1 : acc0;
#pragma unroll
      for (int r = 0; r < 4; ++r) {
        int mrow = (int)(grow) + mt*16 + quad*4 + r;
        out[(size_t)mrow*CIN + ct*16 + l15] = a[r] + bov;
      }
    }
  }
}

extern "C" void kernel_launch(void* const* d_in, const int* in_sizes, int n_in,
                              void* d_out, int out_size, void* d_ws, size_t ws_size,
                              hipStream_t stream) {
  (void)in_sizes; (void)n_in; (void)out_size; (void)ws_size;
  const float* x    = (const float*)d_in[0];
  const float* sinp = (const float*)d_in[1];
  const float* gam  = (const float*)d_in[2];
  const float* bet  = (const float*)d_in[3];
  const float* Wq1  = (const float*)d_in[4];
  const float* Wq2  = (const float*)d_in[5];
  const float* Wq3  = (const float*)d_in[6];
  const float* Wk1  = (const float*)d_in[7];
  const float* Wk2  = (const float*)d_in[8];
  const float* Wk3  = (const float*)d_in[9];
  const float* Wqa  = (const float*)d_in[10];
  const float* Wka  = (const float*)d_in[11];
  const float* Wva  = (const float*)d_in[12];
  const float* Wg   = (const float*)d_in[13];
  const float* bg   = (const float*)d_in[14];
  const float* Wo   = (const float*)d_in[15];
  const float* bo   = (const float*)d_in[16];
  float* out = (float*)d_out;

  char* w = (char*)d_ws;
  auto carve = [&](size_t bytes) { char* p = w; w += (bytes + 255) & ~(size_t)255; return p; };
  f16*   xn    = (f16*)carve((size_t)NN*CIN*2);    // reused as o after k_proj
  f16*   qb    = (f16*)carve((size_t)NN*CIN*2);
  f16*   kb    = (f16*)carve((size_t)NN*CIN*2);
  f16*   vb    = (f16*)carve((size_t)NN*CIN*2);
  f16*   gbuf  = (f16*)carve((size_t)NN*CIN*2);
  float* bias4 = (float*)carve((size_t)NH*NSEQ*NSEQ*4);
  float* rowm  = (float*)carve((size_t)NSEQ*CIN*4);
  float* colm  = (float*)carve((size_t)NSEQ*CIN*4);
  float* qbT   = (float*)carve((size_t)(NH*RNK)*NSEQ*4);
  float* kbT   = (float*)carve((size_t)(NH*RNK)*NSEQ*4);
  f16*   W4T   = (f16*)carve((size_t)512*CIN*2);
  f16*   WoT   = (f16*)carve((size_t)CIN*CIN*2);
  f16*   wmlp  = (f16*)carve((size_t)WMLP_TOT*2);
  f16*   obuf  = xn;

  hipMemsetAsync(rowm, 0, (size_t)NSEQ*CIN*4, stream);
  k_convert<<<320, 256, 0, stream>>>(Wqa, Wka, Wva, Wg, Wo, W4T, WoT);
  k_convert2<<<WMLP_TOT/256, 256, 0, stream>>>(Wq1, Wq2, Wq3, Wk1, Wk2, Wk3, wmlp);
  k_ln<<<NSEQ*4, 256, 0, stream>>>(x, gam, bet, xn, rowm);
  k_colmean<<<NSEQ, 256, 0, stream>>>(xn, colm);
  k_mlp2<<<24, 256, 0, stream>>>(rowm, colm, sinp, wmlp, qbT, kbT);
  k_bias<<<NH*96, 128, 0, stream>>>(qbT, kbT, bias4);
  k_proj<<<1152, 256, 0, stream>>>(xn, W4T, bg, qb, kb, vb, gbuf);
  k_attn<<<NH*NSEQ*4, 64, 0, stream>>>(qb, kb, vb, bias4, obuf);
  k_final<<<1152, 256, 0, stream>>>(gbuf, obuf, WoT, bo, out);
}

// Round 13
// 433.256 us; speedup vs baseline: 2.3974x; 2.3974x over previous
//
#include <hip/hip_runtime.h>
#include <cstdint>
#include <cstddef>

typedef _Float16 f16;
typedef __attribute__((ext_vector_type(2))) _Float16 f16x2;
typedef __attribute__((ext_vector_type(4))) _Float16 f16x4;
typedef __attribute__((ext_vector_type(8))) _Float16 f16x8;
typedef __attribute__((ext_vector_type(4))) float f32x4;

#define MFMA_16x16x32(a,b,c) __builtin_amdgcn_mfma_f32_16x16x32_f16((a),(b),(c),0,0,0)
#define MFMA_16x16x16(a,b,c) __builtin_amdgcn_mfma_f32_16x16x16f16((a),(b),(c),0,0,0)

#define NSEQ 384
#define CIN 128
#define NH 4
#define DHD 32
#define RNK 96
#define SDIM 449
#define MHID 256
#define NN (NSEQ*NSEQ)
#define LOG2E 1.4426950408889634f

#define KPAD 608            // 577 padded to 19*32
#define ZSTR 616            // LDS stride for z (2-way bank aliasing only)
#define HSTR 264            // LDS stride for h1/h2
// f16 transposed-weight pool offsets (elements)
#define OFF_W1 0
#define SZ_W1 (MHID*KPAD)          // 155648 per matrix
#define OFF_W2 (2*SZ_W1)           // 311296
#define SZ_W2 (MHID*MHID)          // 65536
#define OFF_W3 (OFF_W2 + 2*SZ_W2)  // 442368
#define SZ_W3 ((NH*RNK)*MHID)      // 98304
#define WMLP_TOT (OFF_W3 + 2*SZ_W3) // 638976

// ---------------- weight conversion: W4T[col][k] = W*[k][col&127] (f16), WoT[c][hd] = Wo[hd][c]
__global__ __launch_bounds__(256) void k_convert(const float* __restrict__ Wq, const float* __restrict__ Wk,
    const float* __restrict__ Wv, const float* __restrict__ Wg, const float* __restrict__ Wo,
    f16* __restrict__ W4T, f16* __restrict__ WoT) {
  int idx = blockIdx.x*256 + threadIdx.x;   // 0..81919 (640*128)
  int c = idx >> 7, kk = idx & 127;
  if (c < 512) {
    int mat = c >> 7, cc = c & 127;
    const float* src = mat==0 ? Wq : (mat==1 ? Wk : (mat==2 ? Wv : Wg));
    W4T[c*CIN + kk] = (f16)src[kk*CIN + cc];
  } else {
    int cc = c - 512;
    WoT[cc*CIN + kk] = (f16)Wo[kk*CIN + cc];
  }
}

// ---------------- MLP weight transpose+cast into one f16 pool (coalesced writes)
__global__ __launch_bounds__(256) void k_convert2(const float* __restrict__ Wq1, const float* __restrict__ Wq2,
    const float* __restrict__ Wq3, const float* __restrict__ Wk1, const float* __restrict__ Wk2,
    const float* __restrict__ Wk3, f16* __restrict__ wmlp) {
  int idx = blockIdx.x*256 + threadIdx.x;   // 0..638975
  float val;
  if (idx < OFF_W2) {
    int m = idx / SZ_W1, r = idx - m*SZ_W1;
    int c = r / KPAD, kk = r - c*KPAD;
    const float* src = m ? Wk1 : Wq1;
    val = (kk < SDIM + CIN) ? src[kk*MHID + c] : 0.f;
  } else if (idx < OFF_W3) {
    int r = idx - OFF_W2;
    int m = r >> 16, rr = r & 65535;
    int c = rr >> 8, kk = rr & 255;
    const float* src = m ? Wk2 : Wq2;
    val = src[kk*MHID + c];
  } else {
    int r = idx - OFF_W3;
    int m = r / SZ_W3, rr = r - m*SZ_W3;
    int c = rr >> 8, kk = rr & 255;
    const float* src = m ? Wk3 : Wq3;
    val = src[kk*(NH*RNK) + c];
  }
  wmlp[idx] = (f16)val;
}

// ---------------- layernorm + row-mean contribution. 4 blocks per row i; wave handles 2 rows/iter
__global__ __launch_bounds__(256) void k_ln(const float* __restrict__ x, const float* __restrict__ gamma,
    const float* __restrict__ beta, f16* __restrict__ xn, float* __restrict__ rowm) {
  int b = blockIdx.x;
  int i = b >> 2, jbase = (b & 3) * 96;
  int t = threadIdx.x, wave = t >> 6, lane = t & 63;
  int half = lane >> 5, l31 = lane & 31;
  int c0 = l31 * 4;
  __shared__ float racc[CIN];
  if (t < CIN) racc[t] = 0.f;
  float4 g4 = *(const float4*)&gamma[c0];
  float4 b4 = *(const float4*)&beta[c0];
  float a0=0,a1=0,a2=0,a3=0;
  __syncthreads();
  for (int it = 0; it < 12; ++it) {
    int j = jbase + it*8 + wave*2 + half;
    const float4 v = *(const float4*)&x[(size_t)(i*NSEQ + j)*CIN + c0];
    float s = (v.x+v.y)+(v.z+v.w);
    float ss = (v.x*v.x+v.y*v.y)+(v.z*v.z+v.w*v.w);
#pragma unroll
    for (int off = 16; off >= 1; off >>= 1) { s += __shfl_xor(s, off); ss += __shfl_xor(ss, off); }
    float mean = s * (1.0f/CIN);
    float var = ss * (1.0f/CIN) - mean*mean;
    float rs = rsqrtf(var + 1e-5f);
    float y0 = (v.x-mean)*rs*g4.x + b4.x;
    float y1 = (v.y-mean)*rs*g4.y + b4.y;
    float y2 = (v.z-mean)*rs*g4.z + b4.z;
    float y3 = (v.w-mean)*rs*g4.w + b4.w;
    f16x4 w; w[0]=(f16)y0; w[1]=(f16)y1; w[2]=(f16)y2; w[3]=(f16)y3;
    *(f16x4*)&xn[(size_t)(i*NSEQ + j)*CIN + c0] = w;
    a0+=y0; a1+=y1; a2+=y2; a3+=y3;
  }
  atomicAdd(&racc[c0], a0); atomicAdd(&racc[c0+1], a1);
  atomicAdd(&racc[c0+2], a2); atomicAdd(&racc[c0+3], a3);
  __syncthreads();
  if (t < CIN) atomicAdd(&rowm[i*CIN + t], racc[t] * (1.0f/NSEQ));
}

// ---------------- column means v2 (mean over axis 0), f16x8 vector loads. 16 slices x 24 rows.
__global__ __launch_bounds__(256) void k_colmean(const f16* __restrict__ xn, float* __restrict__ colm) {
  int j = blockIdx.x; int t = threadIdx.x;
  int cg = (t & 15) * 8;      // channel group base (16 groups x 8 ch)
  int s  = t >> 4;            // slice 0..15, 24 rows each
  float acc[8];
#pragma unroll
  for (int u = 0; u < 8; ++u) acc[u] = 0.f;
  int i0 = s * 24;
  for (int ii = i0; ii < i0 + 24; ++ii) {
    f16x8 v = *(const f16x8*)&xn[(size_t)(ii*NSEQ + j)*CIN + cg];
#pragma unroll
    for (int u = 0; u < 8; ++u) acc[u] += (float)v[u];
  }
  __shared__ float sb[16][CIN];
#pragma unroll
  for (int u = 0; u < 8; ++u) sb[s][cg + u] = acc[u];
  __syncthreads();
  if (t < 128) {
    float r = 0.f;
#pragma unroll
    for (int s2 = 0; s2 < 16; ++s2) r += sb[s2][t];
    colm[j*CIN + t] = r * (1.0f/NSEQ);
  }
}

// ---------------- fused bias MLP (MFMA): 32 rows/block, 3 layers block-local. fp32 qbT/kbT out.
__global__ __launch_bounds__(256) void k_mlp2(const float* __restrict__ rowm, const float* __restrict__ colm,
    const float* __restrict__ sinp, const f16* __restrict__ wmlp,
    float* __restrict__ qbT, float* __restrict__ kbT) {
  int b = blockIdx.x;
  bool isQ = b < 12;
  int r0 = (isQ ? b : b - 12) * 32;
  const float* mean = isQ ? rowm : colm;
  const f16* W1T = wmlp + (isQ ? 0 : SZ_W1);
  const f16* W2T = wmlp + OFF_W2 + (isQ ? 0 : SZ_W2);
  const f16* W3T = wmlp + OFF_W3 + (isQ ? 0 : SZ_W3);
  float* outp = isQ ? qbT : kbT;
  int t = threadIdx.x, wave = t >> 6, lane = t & 63;
  int l15 = lane & 15, quad = lane >> 4;
  int rt = wave & 1, ch = wave >> 1;   // row-tile, col-half

  __shared__ __align__(16) f16 z[32*ZSTR];
  __shared__ __align__(16) f16 hbuf[2][32*HSTR];

  for (int idx = t; idx < 32*KPAD; idx += 256) {
    int row = idx / KPAD, u = idx - row*KPAD;
    float v;
    if (u < CIN) v = mean[(r0+row)*CIN + u];
    else if (u < CIN + SDIM) v = sinp[(r0+row)*SDIM + (u - CIN)];
    else v = 0.f;
    z[row*ZSTR + u] = (f16)v;
  }
  __syncthreads();

  {
    f32x4 acc[8];
#pragma unroll
    for (int c = 0; c < 8; ++c) acc[c] = (f32x4){0,0,0,0};
    for (int ks = 0; ks < 19; ++ks) {
      f16x8 af = *(const f16x8*)&z[(rt*16 + l15)*ZSTR + ks*32 + quad*8];
#pragma unroll
      for (int c = 0; c < 8; ++c) {
        f16x8 bf = *(const f16x8*)&W1T[(size_t)((ch*8 + c)*16 + l15)*KPAD + ks*32 + quad*8];
        acc[c] = MFMA_16x16x32(af, bf, acc[c]);
      }
    }
#pragma unroll
    for (int c = 0; c < 8; ++c) {
      int col = (ch*8 + c)*16 + l15;
#pragma unroll
      for (int r = 0; r < 4; ++r) {
        float th = 1.f - 2.f/(1.f + __expf(2.f*acc[c][r]));
        hbuf[0][(rt*16 + quad*4 + r)*HSTR + col] = (f16)th;
      }
    }
  }
  __syncthreads();

  {
    f32x4 acc[8];
#pragma unroll
    for (int c = 0; c < 8; ++c) acc[c] = (f32x4){0,0,0,0};
    for (int ks = 0; ks < 8; ++ks) {
      f16x8 af = *(const f16x8*)&hbuf[0][(rt*16 + l15)*HSTR + ks*32 + quad*8];
#pragma unroll
      for (int c = 0; c < 8; ++c) {
        f16x8 bf = *(const f16x8*)&W2T[(size_t)((ch*8 + c)*16 + l15)*MHID + ks*32 + quad*8];
        acc[c] = MFMA_16x16x32(af, bf, acc[c]);
      }
    }
#pragma unroll
    for (int c = 0; c < 8; ++c) {
      int col = (ch*8 + c)*16 + l15;
#pragma unroll
      for (int r = 0; r < 4; ++r) {
        float th = 1.f - 2.f/(1.f + __expf(2.f*acc[c][r]));
        hbuf[1][(rt*16 + quad*4 + r)*HSTR + col] = (f16)th;
      }
    }
  }
  __syncthreads();

  {
    f32x4 acc[12];
#pragma unroll
    for (int c = 0; c < 12; ++c) acc[c] = (f32x4){0,0,0,0};
    for (int ks = 0; ks < 8; ++ks) {
      f16x8 af = *(const f16x8*)&hbuf[1][(rt*16 + l15)*HSTR + ks*32 + quad*8];
#pragma unroll
      for (int c = 0; c < 12; ++c) {
        f16x8 bf = *(const f16x8*)&W3T[(size_t)((ch*12 + c)*16 + l15)*MHID + ks*32 + quad*8];
        acc[c] = MFMA_16x16x32(af, bf, acc[c]);
      }
    }
#pragma unroll
    for (int c = 0; c < 12; ++c) {
      int o = (ch*12 + c)*16 + l15;
#pragma unroll
      for (int r = 0; r < 4; ++r)
        outp[o*NSEQ + r0 + rt*16 + quad*4 + r] = acc[c][r];
    }
  }
}

// ---------------- low-rank bias outer product into MFMA C-fragment layout (fp32, pre-scaled by LOG2E):
// bias4[h][k>>2][q][k&3]; block = (h, kgroup), 128 threads x 3 q each.
__global__ __launch_bounds__(128) void k_bias(const float* __restrict__ qbT, const float* __restrict__ kbT,
    float* __restrict__ bias4) {
  int b = blockIdx.x;            // h*96 + kg
  int h = b / 96, kg = b - h*96;
  int t = threadIdx.x;
  __shared__ float4 kr[RNK];
  if (t < RNK) kr[t] = *(const float4*)&kbT[(size_t)(h*RNK + t)*NSEQ + kg*4];
  __syncthreads();
  float acc[3][4];
#pragma unroll
  for (int m = 0; m < 3; ++m)
#pragma unroll
    for (int r = 0; r < 4; ++r) acc[m][r] = 0.f;
  for (int r = 0; r < RNK; ++r) {
    float4 kv = kr[r];
    const float* qrow = qbT + (size_t)(h*RNK + r)*NSEQ;
    float q0 = qrow[t], q1 = qrow[t+128], q2 = qrow[t+256];
    acc[0][0]+=q0*kv.x; acc[0][1]+=q0*kv.y; acc[0][2]+=q0*kv.z; acc[0][3]+=q0*kv.w;
    acc[1][0]+=q1*kv.x; acc[1][1]+=q1*kv.y; acc[1][2]+=q1*kv.z; acc[1][3]+=q1*kv.w;
    acc[2][0]+=q2*kv.x; acc[2][1]+=q2*kv.y; acc[2][2]+=q2*kv.z; acc[2][3]+=q2*kv.w;
  }
#pragma unroll
  for (int m = 0; m < 3; ++m) {
    int q = t + m*128;
    f32x4 w; w[0]=acc[m][0]*LOG2E; w[1]=acc[m][1]*LOG2E; w[2]=acc[m][2]*LOG2E; w[3]=acc[m][3]*LOG2E;
    *(f32x4*)&bias4[((size_t)b*NSEQ + q)*4] = w;
  }
}

// ---------------- projections (round-3 proven version): hybrid A-in-regs + B-in-LDS.
__global__ __launch_bounds__(256) void k_proj(const f16* __restrict__ xn, const f16* __restrict__ W4T,
    const float* __restrict__ bg, f16* __restrict__ qb, f16* __restrict__ kb, f16* __restrict__ vb,
    f16* __restrict__ gb) {
  int mb = blockIdx.x;              // 0..1151
  int t = threadIdx.x, wave = t >> 6, lane = t & 63;
  int l15 = lane & 15, quad = lane >> 4;
  int m0 = wave*32;                 // wave's row base within the 128-row tile
  __shared__ __align__(16) f16 Bs[128*128];   // 32 KB, XOR-swizzled
  size_t grow = (size_t)mb*128 + m0;
  f16x8 af[2][4];
#pragma unroll
  for (int mt = 0; mt < 2; ++mt)
#pragma unroll
    for (int kt = 0; kt < 4; ++kt)
      af[mt][kt] = *(const f16x8*)&xn[(grow + mt*16 + l15)*CIN + (kt*4 + quad)*8];
  int i = mb/3, j0 = (mb - (mb/3)*3)*128 + m0;
  for (int nb = 0; nb < 4; ++nb) {
    for (int p = 0; p < 8; ++p) {
      int c = p*256 + t; int row = c >> 4, ci = c & 15;
      int sw = (ci ^ (row & 15)) * 8;
      *(f16x8*)&Bs[row*128 + sw] = *(const f16x8*)&W4T[(size_t)(nb*128 + row)*CIN + ci*8];
    }
    __syncthreads();
#pragma unroll
    for (int ct = 0; ct < 8; ++ct) {
      f32x4 acc0 = (f32x4){0,0,0,0}, acc1 = (f32x4){0,0,0,0};
#pragma unroll
      for (int kt = 0; kt < 4; ++kt) {
        f16x8 bf = *(const f16x8*)&Bs[(ct*16 + l15)*128 + ((kt*4 + quad) ^ l15)*8];
        acc0 = MFMA_16x16x32(af[0][kt], bf, acc0);
        acc1 = MFMA_16x16x32(af[1][kt], bf, acc1);
      }
      int col = nb*128 + ct*16 + l15;
      int cc = col & 127;
      int hh = cc >> 5, d = cc & 31;
      if (nb == 3) {
        float bgv = bg[cc];
#pragma unroll
        for (int mt = 0; mt < 2; ++mt) {
          f32x4 a = mt ? acc1 : acc0;
#pragma unroll
          for (int r = 0; r < 4; ++r) {
            int jj = j0 + mt*16 + quad*4 + r;
            float sg = 1.0f/(1.0f + __expf(-(a[r] + bgv)));
            gb[(size_t)(i*NSEQ + jj)*CIN + cc] = (f16)sg;
          }
        }
      } else {
        f16* dstb = nb==0 ? qb : (nb==1 ? kb : vb);
        float scale = nb==0 ? 0.25503576722f : 1.0f;   // log2e / sqrt(32)
#pragma unroll
        for (int mt = 0; mt < 2; ++mt) {
          f32x4 a = mt ? acc1 : acc0;
#pragma unroll
          for (int r = 0; r < 4; ++r) {
            int jj = j0 + mt*16 + quad*4 + r;
            dstb[((size_t)(i*NH + hh)*NSEQ + jj)*DHD + d] = (f16)(a[r]*scale);
          }
        }
      }
    }
    __syncthreads();
  }
}

// ---------------- attention v11: round-2 body, one wave per block (grid 6144, 64 threads).
// r12 retry WITHOUT the min-waves pin: launch_bounds(64) only, so the allocator is free to use
// the ~64 VGPR this body needs (r12's (64,8) pinned 32 VGPR -> total spill, 695 us; but its 56%
// occupancy showed single-wave packing works). At 64 VGPR the HW supports 8 waves/SIMD anyway.
__global__ __launch_bounds__(64) void k_attn(const f16* __restrict__ qg, const f16* __restrict__ kg,
    const f16* __restrict__ vg, const float* __restrict__ bias4, f16* __restrict__ og) {
  int b = blockIdx.x;                       // h*(NSEQ*4) + i*4 + w
  int h = b / (NSEQ*4); int r = b - h*(NSEQ*4);
  int i = r >> 2; int wave = r & 3;
  int lane = threadIdx.x & 63;
  int l15 = lane & 15, quad = lane >> 4;
  size_t base = (size_t)(i*NH + h) * NSEQ * DHD;
  int qt0 = wave*6;
  f16x8 qf[6];
#pragma unroll
  for (int s = 0; s < 6; ++s)
    qf[s] = *(const f16x8*)&qg[base + (size_t)((qt0+s)*16 + l15)*DHD + quad*8];
  f32x4 oa[6][2];
  float lsum[6];
#pragma unroll
  for (int s = 0; s < 6; ++s) { lsum[s] = 0.f; oa[s][0] = (f32x4){0,0,0,0}; oa[s][1] = (f32x4){0,0,0,0}; }
  const f16* kp = kg + base + (size_t)l15*DHD + quad*8;
  const f16* vp = vg + base + (size_t)(quad*4)*DHD + l15;
  const float* bp = bias4 + (((size_t)h*96 + quad)*NSEQ + qt0*16 + l15)*4;
  for (int kt = 0; kt < 24; ++kt) {
    f16x8 kf = *(const f16x8*)kp;
    f16x4 vf0, vf1;
#pragma unroll
    for (int jj = 0; jj < 4; ++jj) { vf0[jj] = vp[jj*DHD]; vf1[jj] = vp[jj*DHD + 16]; }
    f32x4 cb[6];
#pragma unroll
    for (int s = 0; s < 6; ++s) cb[s] = *(const f32x4*)(bp + s*64);
    kp += 16*DHD; vp += 16*DHD; bp += 4*NSEQ*4;
#pragma unroll
    for (int s = 0; s < 6; ++s) {
      f32x4 st = MFMA_16x16x32(kf, qf[s], cb[s]);   // S^T tile: row=k, col=q (bias via C-init)
      float p0 = __builtin_amdgcn_exp2f(st[0]);
      float p1 = __builtin_amdgcn_exp2f(st[1]);
      float p2 = __builtin_amdgcn_exp2f(st[2]);
      float p3 = __builtin_amdgcn_exp2f(st[3]);
      lsum[s] += (p0 + p1) + (p2 + p3);
      f16x4 pa; pa[0]=(f16)p0; pa[1]=(f16)p1; pa[2]=(f16)p2; pa[3]=(f16)p3;
      oa[s][0] = MFMA_16x16x16(pa, vf0, oa[s][0]);  // C-layout of S^T == A-layout for K=16 MFMA
      oa[s][1] = MFMA_16x16x16(pa, vf1, oa[s][1]);
    }
  }
#pragma unroll
  for (int s = 0; s < 6; ++s) {
    float lf = lsum[s];
    lf += __shfl_xor(lf, 16);
    lf += __shfl_xor(lf, 32);
    float inv = 1.0f / lf;   // valid for q = l15
#pragma unroll
    for (int r2 = 0; r2 < 4; ++r2) {
      float invr = __shfl(inv, quad*4 + r2);
      int qrow = (qt0+s)*16 + quad*4 + r2;
      size_t ob = (size_t)(i*NSEQ + qrow)*(NH*DHD) + h*DHD;
      og[ob + l15]      = (f16)(oa[s][0][r2] * invr);
      og[ob + 16 + l15] = (f16)(oa[s][1][r2] * invr);
    }
  }
}

// ---------------- final v2: out = (g*o) @ Wo + bo. A (=g*o) fragments built directly in registers
// from global; only the 32 KB WoT tile staged in LDS.
__global__ __launch_bounds__(256) void k_final(const f16* __restrict__ gb, const f16* __restrict__ ob,
    const f16* __restrict__ WoT, const float* __restrict__ bo, float* __restrict__ out) {
  int mb = blockIdx.x;
  int t = threadIdx.x, wave = t >> 6, lane = t & 63;
  int l15 = lane & 15, quad = lane >> 4;
  __shared__ __align__(16) f16 Bs[128*128];
  for (int p = 0; p < 8; ++p) {
    int c = p*256 + t; int row = c >> 4, ci = c & 15;
    int sw = (ci ^ (row & 15)) * 8;
    *(f16x8*)&Bs[row*128 + sw] = *(const f16x8*)&WoT[row*CIN + ci*8];
  }
  int m0 = wave*32;
  size_t grow = (size_t)mb*128 + m0;
  f16x8 af[2][4];
#pragma unroll
  for (int mt = 0; mt < 2; ++mt)
#pragma unroll
    for (int kt = 0; kt < 4; ++kt) {
      size_t off = (grow + mt*16 + l15)*CIN + (kt*4 + quad)*8;
      f16x8 gv = *(const f16x8*)&gb[off];
      f16x8 ov = *(const f16x8*)&ob[off];
      af[mt][kt] = gv*ov;
    }
  __syncthreads();
#pragma unroll
  for (int ct = 0; ct < 8; ++ct) {
    f32x4 acc0 = (f32x4){0,0,0,0}, acc1 = (f32x4){0,0,0,0};
#pragma unroll
    for (int kt = 0; kt < 4; ++kt) {
      f16x8 bf = *(const f16x8*)&Bs[(ct*16 + l15)*128 + ((kt*4 + quad) ^ l15)*8];
      acc0 = MFMA_16x16x32(af[0][kt], bf, acc0);
      acc1 = MFMA_16x16x32(af[1][kt], bf, acc1);
    }
    float bov = bo[ct*16 + l15];
#pragma unroll
    for (int mt = 0; mt < 2; ++mt) {
      f32x4 a = mt ? acc1 : acc0;
#pragma unroll
      for (int r = 0; r < 4; ++r) {
        int mrow = (int)(grow) + mt*16 + quad*4 + r;
        out[(size_t)mrow*CIN + ct*16 + l15] = a[r] + bov;
      }
    }
  }
}

extern "C" void kernel_launch(void* const* d_in, const int* in_sizes, int n_in,
                              void* d_out, int out_size, void* d_ws, size_t ws_size,
                              hipStream_t stream) {
  (void)in_sizes; (void)n_in; (void)out_size; (void)ws_size;
  const float* x    = (const float*)d_in[0];
  const float* sinp = (const float*)d_in[1];
  const float* gam  = (const float*)d_in[2];
  const float* bet  = (const float*)d_in[3];
  const float* Wq1  = (const float*)d_in[4];
  const float* Wq2  = (const float*)d_in[5];
  const float* Wq3  = (const float*)d_in[6];
  const float* Wk1  = (const float*)d_in[7];
  const float* Wk2  = (const float*)d_in[8];
  const float* Wk3  = (const float*)d_in[9];
  const float* Wqa  = (const float*)d_in[10];
  const float* Wka  = (const float*)d_in[11];
  const float* Wva  = (const float*)d_in[12];
  const float* Wg   = (const float*)d_in[13];
  const float* bg   = (const float*)d_in[14];
  const float* Wo   = (const float*)d_in[15];
  const float* bo   = (const float*)d_in[16];
  float* out = (float*)d_out;

  char* w = (char*)d_ws;
  auto carve = [&](size_t bytes) { char* p = w; w += (bytes + 255) & ~(size_t)255; return p; };
  f16*   xn    = (f16*)carve((size_t)NN*CIN*2);    // reused as o after k_proj
  f16*   qb    = (f16*)carve((size_t)NN*CIN*2);
  f16*   kb    = (f16*)carve((size_t)NN*CIN*2);
  f16*   vb    = (f16*)carve((size_t)NN*CIN*2);
  f16*   gbuf  = (f16*)carve((size_t)NN*CIN*2);
  float* bias4 = (float*)carve((size_t)NH*NSEQ*NSEQ*4);
  float* rowm  = (float*)carve((size_t)NSEQ*CIN*4);
  float* colm  = (float*)carve((size_t)NSEQ*CIN*4);
  float* qbT   = (float*)carve((size_t)(NH*RNK)*NSEQ*4);
  float* kbT   = (float*)carve((size_t)(NH*RNK)*NSEQ*4);
  f16*   W4T   = (f16*)carve((size_t)512*CIN*2);
  f16*   WoT   = (f16*)carve((size_t)CIN*CIN*2);
  f16*   wmlp  = (f16*)carve((size_t)WMLP_TOT*2);
  f16*   obuf  = xn;

  hipMemsetAsync(rowm, 0, (size_t)NSEQ*CIN*4, stream);
  k_convert<<<320, 256, 0, stream>>>(Wqa, Wka, Wva, Wg, Wo, W4T, WoT);
  k_convert2<<<WMLP_TOT/256, 256, 0, stream>>>(Wq1, Wq2, Wq3, Wk1, Wk2, Wk3, wmlp);
  k_ln<<<NSEQ*4, 256, 0, stream>>>(x, gam, bet, xn, rowm);
  k_colmean<<<NSEQ, 256, 0, stream>>>(xn, colm);
  k_mlp2<<<24, 256, 0, stream>>>(rowm, colm, sinp, wmlp, qbT, kbT);
  k_bias<<<NH*96, 128, 0, stream>>>(qbT, kbT, bias4);
  k_proj<<<1152, 256, 0, stream>>>(xn, W4T, bg, qb, kb, vb, gbuf);
  k_attn<<<NH*NSEQ*4, 64, 0, stream>>>(qb, kb, vb, bias4, obuf);
  k_final<<<1152, 256, 0, stream>>>(gbuf, obuf, WoT, bo, out);
}

// Round 15
// 424.942 us; speedup vs baseline: 2.4443x; 1.0196x over previous
//
#include <hip/hip_runtime.h>
#include <cstdint>
#include <cstddef>

typedef _Float16 f16;
typedef __attribute__((ext_vector_type(2))) _Float16 f16x2;
typedef __attribute__((ext_vector_type(4))) _Float16 f16x4;
typedef __attribute__((ext_vector_type(8))) _Float16 f16x8;
typedef __attribute__((ext_vector_type(4))) float f32x4;

#define MFMA_16x16x32(a,b,c) __builtin_amdgcn_mfma_f32_16x16x32_f16((a),(b),(c),0,0,0)
#define MFMA_16x16x16(a,b,c) __builtin_amdgcn_mfma_f32_16x16x16f16((a),(b),(c),0,0,0)

#define NSEQ 384
#define CIN 128
#define NH 4
#define DHD 32
#define RNK 96
#define SDIM 449
#define MHID 256
#define NN (NSEQ*NSEQ)
#define LOG2E 1.4426950408889634f

#define KPAD 608            // 577 padded to 19*32
#define ZSTR 616            // LDS stride for z (2-way bank aliasing only)
#define HSTR 264            // LDS stride for h1/h2
// f16 transposed-weight pool offsets (elements)
#define OFF_W1 0
#define SZ_W1 (MHID*KPAD)          // 155648 per matrix
#define OFF_W2 (2*SZ_W1)           // 311296
#define SZ_W2 (MHID*MHID)          // 65536
#define OFF_W3 (OFF_W2 + 2*SZ_W2)  // 442368
#define SZ_W3 ((NH*RNK)*MHID)      // 98304
#define WMLP_TOT (OFF_W3 + 2*SZ_W3) // 638976

// ---------------- weight conversion: W4T[col][k] = W*[k][col&127] (f16), WoT[c][hd] = Wo[hd][c]
__global__ __launch_bounds__(256) void k_convert(const float* __restrict__ Wq, const float* __restrict__ Wk,
    const float* __restrict__ Wv, const float* __restrict__ Wg, const float* __restrict__ Wo,
    f16* __restrict__ W4T, f16* __restrict__ WoT) {
  int idx = blockIdx.x*256 + threadIdx.x;   // 0..81919 (640*128)
  int c = idx >> 7, kk = idx & 127;
  if (c < 512) {
    int mat = c >> 7, cc = c & 127;
    const float* src = mat==0 ? Wq : (mat==1 ? Wk : (mat==2 ? Wv : Wg));
    W4T[c*CIN + kk] = (f16)src[kk*CIN + cc];
  } else {
    int cc = c - 512;
    WoT[cc*CIN + kk] = (f16)Wo[kk*CIN + cc];
  }
}

// ---------------- MLP weight transpose+cast into one f16 pool (coalesced writes)
__global__ __launch_bounds__(256) void k_convert2(const float* __restrict__ Wq1, const float* __restrict__ Wq2,
    const float* __restrict__ Wq3, const float* __restrict__ Wk1, const float* __restrict__ Wk2,
    const float* __restrict__ Wk3, f16* __restrict__ wmlp) {
  int idx = blockIdx.x*256 + threadIdx.x;   // 0..638975
  float val;
  if (idx < OFF_W2) {
    int m = idx / SZ_W1, r = idx - m*SZ_W1;
    int c = r / KPAD, kk = r - c*KPAD;
    const float* src = m ? Wk1 : Wq1;
    val = (kk < SDIM + CIN) ? src[kk*MHID + c] : 0.f;
  } else if (idx < OFF_W3) {
    int r = idx - OFF_W2;
    int m = r >> 16, rr = r & 65535;
    int c = rr >> 8, kk = rr & 255;
    const float* src = m ? Wk2 : Wq2;
    val = src[kk*MHID + c];
  } else {
    int r = idx - OFF_W3;
    int m = r / SZ_W3, rr = r - m*SZ_W3;
    int c = rr >> 8, kk = rr & 255;
    const float* src = m ? Wk3 : Wq3;
    val = src[kk*(NH*RNK) + c];
  }
  wmlp[idx] = (f16)val;
}

// ---------------- layernorm + row-mean contribution. 4 blocks per row i; wave handles 2 rows/iter
__global__ __launch_bounds__(256) void k_ln(const float* __restrict__ x, const float* __restrict__ gamma,
    const float* __restrict__ beta, f16* __restrict__ xn, float* __restrict__ rowm) {
  int b = blockIdx.x;
  int i = b >> 2, jbase = (b & 3) * 96;
  int t = threadIdx.x, wave = t >> 6, lane = t & 63;
  int half = lane >> 5, l31 = lane & 31;
  int c0 = l31 * 4;
  __shared__ float racc[CIN];
  if (t < CIN) racc[t] = 0.f;
  float4 g4 = *(const float4*)&gamma[c0];
  float4 b4 = *(const float4*)&beta[c0];
  float a0=0,a1=0,a2=0,a3=0;
  __syncthreads();
  for (int it = 0; it < 12; ++it) {
    int j = jbase + it*8 + wave*2 + half;
    const float4 v = *(const float4*)&x[(size_t)(i*NSEQ + j)*CIN + c0];
    float s = (v.x+v.y)+(v.z+v.w);
    float ss = (v.x*v.x+v.y*v.y)+(v.z*v.z+v.w*v.w);
#pragma unroll
    for (int off = 16; off >= 1; off >>= 1) { s += __shfl_xor(s, off); ss += __shfl_xor(ss, off); }
    float mean = s * (1.0f/CIN);
    float var = ss * (1.0f/CIN) - mean*mean;
    float rs = rsqrtf(var + 1e-5f);
    float y0 = (v.x-mean)*rs*g4.x + b4.x;
    float y1 = (v.y-mean)*rs*g4.y + b4.y;
    float y2 = (v.z-mean)*rs*g4.z + b4.z;
    float y3 = (v.w-mean)*rs*g4.w + b4.w;
    f16x4 w; w[0]=(f16)y0; w[1]=(f16)y1; w[2]=(f16)y2; w[3]=(f16)y3;
    *(f16x4*)&xn[(size_t)(i*NSEQ + j)*CIN + c0] = w;
    a0+=y0; a1+=y1; a2+=y2; a3+=y3;
  }
  atomicAdd(&racc[c0], a0); atomicAdd(&racc[c0+1], a1);
  atomicAdd(&racc[c0+2], a2); atomicAdd(&racc[c0+3], a3);
  __syncthreads();
  if (t < CIN) atomicAdd(&rowm[i*CIN + t], racc[t] * (1.0f/NSEQ));
}

// ---------------- column means v2 (mean over axis 0), f16x8 vector loads. 16 slices x 24 rows.
__global__ __launch_bounds__(256) void k_colmean(const f16* __restrict__ xn, float* __restrict__ colm) {
  int j = blockIdx.x; int t = threadIdx.x;
  int cg = (t & 15) * 8;      // channel group base (16 groups x 8 ch)
  int s  = t >> 4;            // slice 0..15, 24 rows each
  float acc[8];
#pragma unroll
  for (int u = 0; u < 8; ++u) acc[u] = 0.f;
  int i0 = s * 24;
  for (int ii = i0; ii < i0 + 24; ++ii) {
    f16x8 v = *(const f16x8*)&xn[(size_t)(ii*NSEQ + j)*CIN + cg];
#pragma unroll
    for (int u = 0; u < 8; ++u) acc[u] += (float)v[u];
  }
  __shared__ float sb[16][CIN];
#pragma unroll
  for (int u = 0; u < 8; ++u) sb[s][cg + u] = acc[u];
  __syncthreads();
  if (t < 128) {
    float r = 0.f;
#pragma unroll
    for (int s2 = 0; s2 < 16; ++s2) r += sb[s2][t];
    colm[j*CIN + t] = r * (1.0f/NSEQ);
  }
}

// ---------------- fused bias MLP (MFMA): 32 rows/block, 3 layers block-local. fp32 qbT/kbT out.
__global__ __launch_bounds__(256) void k_mlp2(const float* __restrict__ rowm, const float* __restrict__ colm,
    const float* __restrict__ sinp, const f16* __restrict__ wmlp,
    float* __restrict__ qbT, float* __restrict__ kbT) {
  int b = blockIdx.x;
  bool isQ = b < 12;
  int r0 = (isQ ? b : b - 12) * 32;
  const float* mean = isQ ? rowm : colm;
  const f16* W1T = wmlp + (isQ ? 0 : SZ_W1);
  const f16* W2T = wmlp + OFF_W2 + (isQ ? 0 : SZ_W2);
  const f16* W3T = wmlp + OFF_W3 + (isQ ? 0 : SZ_W3);
  float* outp = isQ ? qbT : kbT;
  int t = threadIdx.x, wave = t >> 6, lane = t & 63;
  int l15 = lane & 15, quad = lane >> 4;
  int rt = wave & 1, ch = wave >> 1;   // row-tile, col-half

  __shared__ __align__(16) f16 z[32*ZSTR];
  __shared__ __align__(16) f16 hbuf[2][32*HSTR];

  for (int idx = t; idx < 32*KPAD; idx += 256) {
    int row = idx / KPAD, u = idx - row*KPAD;
    float v;
    if (u < CIN) v = mean[(r0+row)*CIN + u];
    else if (u < CIN + SDIM) v = sinp[(r0+row)*SDIM + (u - CIN)];
    else v = 0.f;
    z[row*ZSTR + u] = (f16)v;
  }
  __syncthreads();

  {
    f32x4 acc[8];
#pragma unroll
    for (int c = 0; c < 8; ++c) acc[c] = (f32x4){0,0,0,0};
    for (int ks = 0; ks < 19; ++ks) {
      f16x8 af = *(const f16x8*)&z[(rt*16 + l15)*ZSTR + ks*32 + quad*8];
#pragma unroll
      for (int c = 0; c < 8; ++c) {
        f16x8 bf = *(const f16x8*)&W1T[(size_t)((ch*8 + c)*16 + l15)*KPAD + ks*32 + quad*8];
        acc[c] = MFMA_16x16x32(af, bf, acc[c]);
      }
    }
#pragma unroll
    for (int c = 0; c < 8; ++c) {
      int col = (ch*8 + c)*16 + l15;
#pragma unroll
      for (int r = 0; r < 4; ++r) {
        float th = 1.f - 2.f/(1.f + __expf(2.f*acc[c][r]));
        hbuf[0][(rt*16 + quad*4 + r)*HSTR + col] = (f16)th;
      }
    }
  }
  __syncthreads();

  {
    f32x4 acc[8];
#pragma unroll
    for (int c = 0; c < 8; ++c) acc[c] = (f32x4){0,0,0,0};
    for (int ks = 0; ks < 8; ++ks) {
      f16x8 af = *(const f16x8*)&hbuf[0][(rt*16 + l15)*HSTR + ks*32 + quad*8];
#pragma unroll
      for (int c = 0; c < 8; ++c) {
        f16x8 bf = *(const f16x8*)&W2T[(size_t)((ch*8 + c)*16 + l15)*MHID + ks*32 + quad*8];
        acc[c] = MFMA_16x16x32(af, bf, acc[c]);
      }
    }
#pragma unroll
    for (int c = 0; c < 8; ++c) {
      int col = (ch*8 + c)*16 + l15;
#pragma unroll
      for (int r = 0; r < 4; ++r) {
        float th = 1.f - 2.f/(1.f + __expf(2.f*acc[c][r]));
        hbuf[1][(rt*16 + quad*4 + r)*HSTR + col] = (f16)th;
      }
    }
  }
  __syncthreads();

  {
    f32x4 acc[12];
#pragma unroll
    for (int c = 0; c < 12; ++c) acc[c] = (f32x4){0,0,0,0};
    for (int ks = 0; ks < 8; ++ks) {
      f16x8 af = *(const f16x8*)&hbuf[1][(rt*16 + l15)*HSTR + ks*32 + quad*8];
#pragma unroll
      for (int c = 0; c < 12; ++c) {
        f16x8 bf = *(const f16x8*)&W3T[(size_t)((ch*12 + c)*16 + l15)*MHID + ks*32 + quad*8];
        acc[c] = MFMA_16x16x32(af, bf, acc[c]);
      }
    }
#pragma unroll
    for (int c = 0; c < 12; ++c) {
      int o = (ch*12 + c)*16 + l15;
#pragma unroll
      for (int r = 0; r < 4; ++r)
        outp[o*NSEQ + r0 + rt*16 + quad*4 + r] = acc[c][r];
    }
  }
}

// ---------------- low-rank bias outer product into MFMA C-fragment layout (fp32, pre-scaled by LOG2E):
// bias4[h][k>>2][q][k&3]; block = (h, kgroup), 128 threads x 3 q each.
__global__ __launch_bounds__(128) void k_bias(const float* __restrict__ qbT, const float* __restrict__ kbT,
    float* __restrict__ bias4) {
  int b = blockIdx.x;            // h*96 + kg
  int h = b / 96, kg = b - h*96;
  int t = threadIdx.x;
  __shared__ float4 kr[RNK];
  if (t < RNK) kr[t] = *(const float4*)&kbT[(size_t)(h*RNK + t)*NSEQ + kg*4];
  __syncthreads();
  float acc[3][4];
#pragma unroll
  for (int m = 0; m < 3; ++m)
#pragma unroll
    for (int r = 0; r < 4; ++r) acc[m][r] = 0.f;
  for (int r = 0; r < RNK; ++r) {
    float4 kv = kr[r];
    const float* qrow = qbT + (size_t)(h*RNK + r)*NSEQ;
    float q0 = qrow[t], q1 = qrow[t+128], q2 = qrow[t+256];
    acc[0][0]+=q0*kv.x; acc[0][1]+=q0*kv.y; acc[0][2]+=q0*kv.z; acc[0][3]+=q0*kv.w;
    acc[1][0]+=q1*kv.x; acc[1][1]+=q1*kv.y; acc[1][2]+=q1*kv.z; acc[1][3]+=q1*kv.w;
    acc[2][0]+=q2*kv.x; acc[2][1]+=q2*kv.y; acc[2][2]+=q2*kv.z; acc[2][3]+=q2*kv.w;
  }
#pragma unroll
  for (int m = 0; m < 3; ++m) {
    int q = t + m*128;
    f32x4 w; w[0]=acc[m][0]*LOG2E; w[1]=acc[m][1]*LOG2E; w[2]=acc[m][2]*LOG2E; w[3]=acc[m][3]*LOG2E;
    *(f32x4*)&bias4[((size_t)b*NSEQ + q)*4] = w;
  }
}

// ---------------- projections (round-3 proven version): hybrid A-in-regs + B-in-LDS.
__global__ __launch_bounds__(256) void k_proj(const f16* __restrict__ xn, const f16* __restrict__ W4T,
    const float* __restrict__ bg, f16* __restrict__ qb, f16* __restrict__ kb, f16* __restrict__ vb,
    f16* __restrict__ gb) {
  int mb = blockIdx.x;              // 0..1151
  int t = threadIdx.x, wave = t >> 6, lane = t & 63;
  int l15 = lane & 15, quad = lane >> 4;
  int m0 = wave*32;                 // wave's row base within the 128-row tile
  __shared__ __align__(16) f16 Bs[128*128];   // 32 KB, XOR-swizzled
  size_t grow = (size_t)mb*128 + m0;
  f16x8 af[2][4];
#pragma unroll
  for (int mt = 0; mt < 2; ++mt)
#pragma unroll
    for (int kt = 0; kt < 4; ++kt)
      af[mt][kt] = *(const f16x8*)&xn[(grow + mt*16 + l15)*CIN + (kt*4 + quad)*8];
  int i = mb/3, j0 = (mb - (mb/3)*3)*128 + m0;
  for (int nb = 0; nb < 4; ++nb) {
    for (int p = 0; p < 8; ++p) {
      int c = p*256 + t; int row = c >> 4, ci = c & 15;
      int sw = (ci ^ (row & 15)) * 8;
      *(f16x8*)&Bs[row*128 + sw] = *(const f16x8*)&W4T[(size_t)(nb*128 + row)*CIN + ci*8];
    }
    __syncthreads();
#pragma unroll
    for (int ct = 0; ct < 8; ++ct) {
      f32x4 acc0 = (f32x4){0,0,0,0}, acc1 = (f32x4){0,0,0,0};
#pragma unroll
      for (int kt = 0; kt < 4; ++kt) {
        f16x8 bf = *(const f16x8*)&Bs[(ct*16 + l15)*128 + ((kt*4 + quad) ^ l15)*8];
        acc0 = MFMA_16x16x32(af[0][kt], bf, acc0);
        acc1 = MFMA_16x16x32(af[1][kt], bf, acc1);
      }
      int col = nb*128 + ct*16 + l15;
      int cc = col & 127;
      int hh = cc >> 5, d = cc & 31;
      if (nb == 3) {
        float bgv = bg[cc];
#pragma unroll
        for (int mt = 0; mt < 2; ++mt) {
          f32x4 a = mt ? acc1 : acc0;
#pragma unroll
          for (int r = 0; r < 4; ++r) {
            int jj = j0 + mt*16 + quad*4 + r;
            float sg = 1.0f/(1.0f + __expf(-(a[r] + bgv)));
            gb[(size_t)(i*NSEQ + jj)*CIN + cc] = (f16)sg;
          }
        }
      } else {
        f16* dstb = nb==0 ? qb : (nb==1 ? kb : vb);
        float scale = nb==0 ? 0.25503576722f : 1.0f;   // log2e / sqrt(32)
#pragma unroll
        for (int mt = 0; mt < 2; ++mt) {
          f32x4 a = mt ? acc1 : acc0;
#pragma unroll
          for (int r = 0; r < 4; ++r) {
            int jj = j0 + mt*16 + quad*4 + r;
            dstb[((size_t)(i*NH + hh)*NSEQ + jj)*DHD + d] = (f16)(a[r]*scale);
          }
        }
      }
    }
    __syncthreads();
  }
}

// ---------------- attention (round-11 exact: proven 72.5 us optimum over 7 tested variants):
// 256-thread blocks (4 waves sharing (i,h) -> L1/L2 locality; single-wave blocks = +2.5x fetch).
__global__ __launch_bounds__(256, 4) void k_attn(const f16* __restrict__ qg, const f16* __restrict__ kg,
    const f16* __restrict__ vg, const float* __restrict__ bias4, f16* __restrict__ og) {
  int b = blockIdx.x; int h = b / NSEQ; int i = b - h*NSEQ;
  int t = threadIdx.x; int wave = t >> 6; int lane = t & 63;
  int l15 = lane & 15, quad = lane >> 4;
  size_t base = (size_t)(i*NH + h) * NSEQ * DHD;
  int qt0 = wave*6;
  f16x8 qf[6];
#pragma unroll
  for (int s = 0; s < 6; ++s)
    qf[s] = *(const f16x8*)&qg[base + (size_t)((qt0+s)*16 + l15)*DHD + quad*8];
  f32x4 oa[6][2];
  float lsum[6];
#pragma unroll
  for (int s = 0; s < 6; ++s) { lsum[s] = 0.f; oa[s][0] = (f32x4){0,0,0,0}; oa[s][1] = (f32x4){0,0,0,0}; }
  const f16* kp = kg + base + (size_t)l15*DHD + quad*8;
  const f16* vp = vg + base + (size_t)(quad*4)*DHD + l15;
  const float* bp = bias4 + (((size_t)h*96 + quad)*NSEQ + qt0*16 + l15)*4;
  for (int kt = 0; kt < 24; ++kt) {
    f16x8 kf = *(const f16x8*)kp;
    f16x4 vf0, vf1;
#pragma unroll
    for (int jj = 0; jj < 4; ++jj) { vf0[jj] = vp[jj*DHD]; vf1[jj] = vp[jj*DHD + 16]; }
    f32x4 cb[6];
#pragma unroll
    for (int s = 0; s < 6; ++s) cb[s] = *(const f32x4*)(bp + s*64);
    kp += 16*DHD; vp += 16*DHD; bp += 4*NSEQ*4;
#pragma unroll
    for (int s = 0; s < 6; ++s) {
      f32x4 st = MFMA_16x16x32(kf, qf[s], cb[s]);   // S^T tile: row=k, col=q (bias via C-init)
      float p0 = __builtin_amdgcn_exp2f(st[0]);
      float p1 = __builtin_amdgcn_exp2f(st[1]);
      float p2 = __builtin_amdgcn_exp2f(st[2]);
      float p3 = __builtin_amdgcn_exp2f(st[3]);
      lsum[s] += (p0 + p1) + (p2 + p3);
      f16x4 pa; pa[0]=(f16)p0; pa[1]=(f16)p1; pa[2]=(f16)p2; pa[3]=(f16)p3;
      oa[s][0] = MFMA_16x16x16(pa, vf0, oa[s][0]);  // C-layout of S^T == A-layout for K=16 MFMA
      oa[s][1] = MFMA_16x16x16(pa, vf1, oa[s][1]);
    }
  }
#pragma unroll
  for (int s = 0; s < 6; ++s) {
    float lf = lsum[s];
    lf += __shfl_xor(lf, 16);
    lf += __shfl_xor(lf, 32);
    float inv = 1.0f / lf;   // valid for q = l15
#pragma unroll
    for (int r = 0; r < 4; ++r) {
      float invr = __shfl(inv, quad*4 + r);
      int qrow = (qt0+s)*16 + quad*4 + r;
      size_t ob = (size_t)(i*NSEQ + qrow)*(NH*DHD) + h*DHD;
      og[ob + l15]      = (f16)(oa[s][0][r] * invr);
      og[ob + 16 + l15] = (f16)(oa[s][1][r] * invr);
    }
  }
}

// ---------------- final v2: out = (g*o) @ Wo + bo. A (=g*o) fragments built directly in registers
// from global; only the 32 KB WoT tile staged in LDS.
__global__ __launch_bounds__(256) void k_final(const f16* __restrict__ gb, const f16* __restrict__ ob,
    const f16* __restrict__ WoT, const float* __restrict__ bo, float* __restrict__ out) {
  int mb = blockIdx.x;
  int t = threadIdx.x, wave = t >> 6, lane = t & 63;
  int l15 = lane & 15, quad = lane >> 4;
  __shared__ __align__(16) f16 Bs[128*128];
  for (int p = 0; p < 8; ++p) {
    int c = p*256 + t; int row = c >> 4, ci = c & 15;
    int sw = (ci ^ (row & 15)) * 8;
    *(f16x8*)&Bs[row*128 + sw] = *(const f16x8*)&WoT[row*CIN + ci*8];
  }
  int m0 = wave*32;
  size_t grow = (size_t)mb*128 + m0;
  f16x8 af[2][4];
#pragma unroll
  for (int mt = 0; mt < 2; ++mt)
#pragma unroll
    for (int kt = 0; kt < 4; ++kt) {
      size_t off = (grow + mt*16 + l15)*CIN + (kt*4 + quad)*8;
      f16x8 gv = *(const f16x8*)&gb[off];
      f16x8 ov = *(const f16x8*)&ob[off];
      af[mt][kt] = gv*ov;
    }
  __syncthreads();
#pragma unroll
  for (int ct = 0; ct < 8; ++ct) {
    f32x4 acc0 = (f32x4){0,0,0,0}, acc1 = (f32x4){0,0,0,0};
#pragma unroll
    for (int kt = 0; kt < 4; ++kt) {
      f16x8 bf = *(const f16x8*)&Bs[(ct*16 + l15)*128 + ((kt*4 + quad) ^ l15)*8];
      acc0 = MFMA_16x16x32(af[0][kt], bf, acc0);
      acc1 = MFMA_16x16x32(af[1][kt], bf, acc1);
    }
    float bov = bo[ct*16 + l15];
#pragma unroll
    for (int mt = 0; mt < 2; ++mt) {
      f32x4 a = mt ? acc1 : acc0;
#pragma unroll
      for (int r = 0; r < 4; ++r) {
        int mrow = (int)(grow) + mt*16 + quad*4 + r;
        out[(size_t)mrow*CIN + ct*16 + l15] = a[r] + bov;
      }
    }
  }
}

extern "C" void kernel_launch(void* const* d_in, const int* in_sizes, int n_in,
                              void* d_out, int out_size, void* d_ws, size_t ws_size,
                              hipStream_t stream) {
  (void)in_sizes; (void)n_in; (void)out_size; (void)ws_size;
  const float* x    = (const float*)d_in[0];
  const float* sinp = (const float*)d_in[1];
  const float* gam  = (const float*)d_in[2];
  const float* bet  = (const float*)d_in[3];
  const float* Wq1  = (const float*)d_in[4];
  const float* Wq2  = (const float*)d_in[5];
  const float* Wq3  = (const float*)d_in[6];
  const float* Wk1  = (const float*)d_in[7];
  const float* Wk2  = (const float*)d_in[8];
  const float* Wk3  = (const float*)d_in[9];
  const float* Wqa  = (const float*)d_in[10];
  const float* Wka  = (const float*)d_in[11];
  const float* Wva  = (const float*)d_in[12];
  const float* Wg   = (const float*)d_in[13];
  const float* bg   = (const float*)d_in[14];
  const float* Wo   = (const float*)d_in[15];
  const float* bo   = (const float*)d_in[16];
  float* out = (float*)d_out;

  char* w = (char*)d_ws;
  auto carve = [&](size_t bytes) { char* p = w; w += (bytes + 255) & ~(size_t)255; return p; };
  f16*   xn    = (f16*)carve((size_t)NN*CIN*2);    // reused as o after k_proj
  f16*   qb    = (f16*)carve((size_t)NN*CIN*2);
  f16*   kb    = (f16*)carve((size_t)NN*CIN*2);
  f16*   vb    = (f16*)carve((size_t)NN*CIN*2);
  f16*   gbuf  = (f16*)carve((size_t)NN*CIN*2);
  float* bias4 = (float*)carve((size_t)NH*NSEQ*NSEQ*4);
  float* rowm  = (float*)carve((size_t)NSEQ*CIN*4);
  float* colm  = (float*)carve((size_t)NSEQ*CIN*4);
  float* qbT   = (float*)carve((size_t)(NH*RNK)*NSEQ*4);
  float* kbT   = (float*)carve((size_t)(NH*RNK)*NSEQ*4);
  f16*   W4T   = (f16*)carve((size_t)512*CIN*2);
  f16*   WoT   = (f16*)carve((size_t)CIN*CIN*2);
  f16*   wmlp  = (f16*)carve((size_t)WMLP_TOT*2);
  f16*   obuf  = xn;

  hipMemsetAsync(rowm, 0, (size_t)NSEQ*CIN*4, stream);
  k_convert<<<320, 256, 0, stream>>>(Wqa, Wka, Wva, Wg, Wo, W4T, WoT);
  k_convert2<<<WMLP_TOT/256, 256, 0, stream>>>(Wq1, Wq2, Wq3, Wk1, Wk2, Wk3, wmlp);
  k_ln<<<NSEQ*4, 256, 0, stream>>>(x, gam, bet, xn, rowm);
  k_colmean<<<NSEQ, 256, 0, stream>>>(xn, colm);
  k_mlp2<<<24, 256, 0, stream>>>(rowm, colm, sinp, wmlp, qbT, kbT);
  k_bias<<<NH*96, 128, 0, stream>>>(qbT, kbT, bias4);
  k_proj<<<1152, 256, 0, stream>>>(xn, W4T, bg, qb, kb, vb, gbuf);
  k_attn<<<NH*NSEQ, 256, 0, stream>>>(qb, kb, vb, bias4, obuf);
  k_final<<<1152, 256, 0, stream>>>(gbuf, obuf, WoT, bo, out);
}